// Round 11
// baseline (293.359 us; speedup 1.0000x reference)
//
#include <hip/hip_runtime.h>
#include <hip/hip_bf16.h>

#define BDIM 2048
#define WDIM 128
#define FDIM 8
#define HDIM 256

typedef __bf16 b8 __attribute__((ext_vector_type(8)));
typedef __bf16 b4 __attribute__((ext_vector_type(4)));
typedef float f32x4 __attribute__((ext_vector_type(4)));

#define L2E  1.44269504088896f
#define L2E2 2.88539008177793f

// workspace layout (bytes), all 16B aligned
#define OFF_RZ  0                 // 256 frags * 1KB (r,z Whh A-frags, pre-scaled by -log2e)
#define OFF_N   262144            // 128 frags * 1KB (n Whh A-frags; nt=0 -> LDS, nt=1 -> L2-streamed)
#define OFF_WIH 393216            // 48 frags * 1KB  (Wih A-frags + bias in k=8, pre-scaled)
#define OFF_WP  442368            // 256 frags * 1KB (Wp B-frags, unscaled)
#define OFF_XB  704512            // 2048*128*8 bf16 = 4194304
// total 4,898,816 B

// dynamic LDS layout (bytes): [0,16K) h dbuf (2x8KB) ; [16K,80K) n-gate nt=0 frags (8w x 8 x 1KB)
// tail overlay: [0,16K) lastb[16][512] bf16 ; [16K,32K) ybuf[16][256] f32
#define SMEM_BYTES 81920

#define MFMA(a,b,c) __builtin_amdgcn_mfma_f32_16x16x32_bf16((a),(b),(c),0,0,0)

static __device__ __forceinline__ float sig_(float v) {      // tail only (unscaled)
    return __builtin_amdgcn_rcpf(1.0f + __expf(-v));
}
static __device__ __forceinline__ float tanh_(float v) {     // tail only (unscaled)
    return fmaf(-2.0f, __builtin_amdgcn_rcpf(1.0f + __expf(2.0f * v)), 1.0f);
}

// ---------------- pack: weights/x -> bf16 MFMA fragments (log2e pre-scaled) ----------------
// A-frag (16x16x32): lane l holds A[i = l&15][k = kt*32 + (l>>4)*8 + e]
// B-frag:            lane l holds B[k = kt*32 + (l>>4)*8 + e][j = l&15]
__global__ void pack_kernel(const float* __restrict__ x,
                            const float* __restrict__ Wih_f,
                            const float* __restrict__ Whh_f,
                            const float* __restrict__ bih_f,
                            const float* __restrict__ bhh_f,
                            const float* __restrict__ Wp,
                            unsigned char* __restrict__ ws)
{
    int idx = blockIdx.x * 256 + threadIdx.x;
    if (idx < 16384) {                       // r,z Whh A-frags: f = (w*4+2g+nt)*8+kt, x(-log2e)
        int l = idx & 63, f = idx >> 6;
        int kt = f & 7, nt = (f >> 3) & 1, g = (f >> 4) & 1, w = f >> 5;
        int gch = g * HDIM + 32 * w + 16 * nt + (l & 15);
        int kb = kt * 32 + (l >> 4) * 8;
        b8 v;
        #pragma unroll
        for (int e = 0; e < 8; ++e) v[e] = (__bf16)(-L2E * Whh_f[gch * HDIM + kb + e]);
        ((b8*)(ws + OFF_RZ))[idx] = v;
    } else if (idx < 24576) {                // n Whh A-frags: f = (w*2+nt)*8+kt, x(2*log2e)
        int j = idx - 16384;
        int l = j & 63, f = j >> 6;
        int kt = f & 7, nt = (f >> 3) & 1, w = f >> 4;
        int gch = 2 * HDIM + 32 * w + 16 * nt + (l & 15);
        int kb = kt * 32 + (l >> 4) * 8;
        b8 v;
        #pragma unroll
        for (int e = 0; e < 8; ++e) v[e] = (__bf16)(L2E2 * Whh_f[gch * HDIM + kb + e]);
        ((b8*)(ws + OFF_N))[j] = v;
    } else if (idx < 27648) {                // Wih A-frags (K=8 real, bias at k=8), pre-scaled
        int j = idx - 24576;
        int l = j & 63, f = j >> 6;
        int nt = f & 1, q = f >> 1, g = q % 3, w = q / 3;
        int gch = g * HDIM + 32 * w + 16 * nt + (l & 15);
        int lq = l >> 4;
        float sc = (g == 2) ? L2E2 : -L2E;
        b8 v;
        #pragma unroll
        for (int e = 0; e < 8; ++e) v[e] = (__bf16)0.0f;
        if (lq == 0) {
            #pragma unroll
            for (int e = 0; e < 8; ++e) v[e] = (__bf16)(sc * Wih_f[gch * FDIM + e]);
        } else if (lq == 1) {
            float b = (g == 2) ? (L2E2 * bih_f[gch]) : (-L2E * (bih_f[gch] + bhh_f[gch]));
            v[0] = (__bf16)b;                // pairs with 1.0 in x B-frag k=8
        }
        ((b8*)(ws + OFF_WIH))[j] = v;
    } else if (idx < 44032) {                // Wp B-frags (unscaled)
        int j = idx - 27648;
        int l = j & 63, nk = j >> 6;
        int NT = nk >> 4, kt = nk & 15;
        int col = NT * 16 + (l & 15);
        int kb = kt * 32 + (l >> 4) * 8;
        b8 v;
        #pragma unroll
        for (int e = 0; e < 8; ++e) v[e] = (__bf16)Wp[col * (2 * HDIM) + kb + e];
        ((b8*)(ws + OFF_WP))[j] = v;
    } else if (idx < 44032 + 262144) {       // x -> bf16 rows [row][t][8]
        int j = idx - 44032;
        const float* src = x + j * 8;
        b8 v;
        #pragma unroll
        for (int e = 0; e < 8; ++e) v[e] = (__bf16)src[e];
        ((b8*)(ws + OFF_XB))[j] = v;
    }
}

// ---------------- fused GRU (transposed MFMA) — round-10 geometry + L2-streamed n1 ----------------
// 128 blocks x 512 threads (8 waves). Block owns 16 batch rows.
// Wave w owns gate channels [32w, 32w+32) of r, z, n.
// r,z Whh + Wih pinned in regs/AGPRs; n nt=0 in LDS; n nt=1 STREAMED FROM L2
// (loop-invariant addresses, depth-4 prefetch) -> halves per-step LDS traffic.
// D[i=gatech][j=batchrow]: lane holds batchrow = l&15, gatech = 4*(l>>4)+j.
__global__ __launch_bounds__(512, 2)
void gru_main_kernel(const float* __restrict__ x,
                     const float* __restrict__ bhh_f,
                     const float* __restrict__ Wih_b, const float* __restrict__ bih_b,
                     const float* __restrict__ bhh_b,
                     const float* __restrict__ bp,
                     const float* __restrict__ gamma, const float* __restrict__ beta,
                     const unsigned char* __restrict__ ws,
                     float* __restrict__ out)
{
    extern __shared__ __align__(16) unsigned char smem[];
    __bf16* hbB = (__bf16*)smem;                            // [0,16K) h dbuf
    b8* nlds = (b8*)(smem + 16384);                         // [16K,80K) n nt=0 frags
    __bf16 (*lastb)[2 * HDIM] = (__bf16(*)[2 * HDIM])smem;  // tail overlay
    float  (*ybuf)[HDIM]      = (float(*)[HDIM])(smem + 16384);

    const int tid = threadIdx.x, lane = tid & 63, w = tid >> 6;
    const int l15 = lane & 15, lq = lane >> 4;
    const int blockRow = blockIdx.x * 16;

    const b8* wsRZ = (const b8*)(ws + OFF_RZ);
    const b8* wsN  = (const b8*)(ws + OFF_N);
    const b8* wsWI = (const b8*)(ws + OFF_WIH);
    const b8* wsWP = (const b8*)(ws + OFF_WP);
    const b8* xB   = (const b8*)(ws + OFF_XB);

    const f32x4 zero4 = {0.f, 0.f, 0.f, 0.f};

    // zero h dbuf: 512 threads x 16B x 2
    *(f32x4*)(smem + tid * 16) = zero4;
    *(f32x4*)(smem + 8192 + tid * 16) = zero4;

    // stage this wave's 8 nt=0 n-gate frags into LDS (one-time)
    {
        const b8* nsrc = wsN + (w * 16) * 64 + lane;        // f = w*16 + kt (nt=0)
        b8* ndst = nlds + (w * 8) * 64 + lane;
        #pragma unroll
        for (int i = 0; i < 8; ++i) ndst[i * 64] = nsrc[i * 64];
    }

    // register-resident A-frags: r,z Whh (32 frags) + Wih (6 frags), PINNED
    b8 whr[2][8], whz[2][8], wir[2], wiz[2], win[2];
    #pragma unroll
    for (int nt = 0; nt < 2; ++nt) {
        #pragma unroll
        for (int kt = 0; kt < 8; ++kt) {
            whr[nt][kt] = wsRZ[((w * 4 + 0 + nt) * 8 + kt) * 64 + lane];
            whz[nt][kt] = wsRZ[((w * 4 + 2 + nt) * 8 + kt) * 64 + lane];
        }
        wir[nt] = wsWI[((w * 3 + 0) * 2 + nt) * 64 + lane];
        wiz[nt] = wsWI[((w * 3 + 1) * 2 + nt) * 64 + lane];
        win[nt] = wsWI[((w * 3 + 2) * 2 + nt) * 64 + lane];
    }
    #pragma unroll
    for (int nt = 0; nt < 2; ++nt) {
        #pragma unroll
        for (int kt = 0; kt < 8; ++kt) {
            asm volatile("" : "+v"(whr[nt][kt]));
            asm volatile("" : "+v"(whz[nt][kt]));
        }
        asm volatile("" : "+v"(wir[nt]));
        asm volatile("" : "+v"(wiz[nt]));
        asm volatile("" : "+v"(win[nt]));
    }

    // bhh_n accumulator-init values, pre-scaled by 2*log2e (C reg j <-> gatech 32w+16nt+4lq+j)
    float4 t0v = *(const float4*)&bhh_f[2 * HDIM + 32 * w + 0  + 4 * lq];
    float4 t1v = *(const float4*)&bhh_f[2 * HDIM + 32 * w + 16 + 4 * lq];
    f32x4 bnv0, bnv1;
    bnv0[0] = L2E2 * t0v.x; bnv0[1] = L2E2 * t0v.y; bnv0[2] = L2E2 * t0v.z; bnv0[3] = L2E2 * t0v.w;
    bnv1[0] = L2E2 * t1v.x; bnv1[1] = L2E2 * t1v.y; bnv1[2] = L2E2 * t1v.z; bnv1[3] = L2E2 * t1v.w;

    // constant part of x B-frag: k=8 -> 1.0 (bias multiplier), rest 0
    b8 xc;
    #pragma unroll
    for (int e = 0; e < 8; ++e) xc[e] = (__bf16)0.0f;
    if (lq == 1) xc[0] = (__bf16)1.0f;

    // h master state in registers: (row=l15, ch=32w+16nt+4lq+j)
    f32x4 h0 = zero4, h1 = zero4;

    const int kswz = (8 * lq) ^ ((l15 & 7) << 3);     // B-read swizzle base
    const int wswz = (l15 & 7) << 3;                  // write swizzle
    const b8* nW = nlds + (w * 8) * 64 + lane;        // nt=0 n frags in LDS
    const b8* nG = wsN + (w * 16 + 8) * 64 + lane;    // nt=1 n frags, L2-streamed
    const b8* xRow = xB + (blockRow + l15) * WDIM;

    // prefetch x for t=0
    b8 xf = xc;
    if (lane < 16) xf = xRow[0];

    __syncthreads();

    int cur = 0;
    for (int t = 0; t < WDIM; ++t) {
        // issue first 4 n1 loads ASAP (L2-resident, loop-invariant addresses);
        // latency covered by x-MFMAs + first kt iterations
        b8 nf[8];
        nf[0] = nG[0 * 64];
        nf[1] = nG[1 * 64];
        nf[2] = nG[2 * 64];
        nf[3] = nG[3 * 64];

        // prefetch next step's x early (hides L2 latency under MFMA)
        b8 xn = xc;
        if (lane < 16) xn = xRow[(t + 1) & 127];

        // x-part MFMAs: register-only operands, fill the post-barrier
        // ds_read latency window; accumulators come out pre-seeded (+ biases via k=8)
        f32x4 aR0 = MFMA(wir[0], xf, zero4);
        f32x4 aR1 = MFMA(wir[1], xf, zero4);
        f32x4 aZ0 = MFMA(wiz[0], xf, zero4);
        f32x4 aZ1 = MFMA(wiz[1], xf, zero4);
        f32x4 aNX0 = MFMA(win[0], xf, zero4);
        f32x4 aNX1 = MFMA(win[1], xf, zero4);
        f32x4 aNH0 = bnv0, aNH1 = bnv1;

        const __bf16* hc = hbB + cur * 4096 + l15 * 256;
        #pragma unroll
        for (int kt = 0; kt < 8; ++kt) {
            b8 hfrag = *(const b8*)(hc + ((kt << 5) ^ kswz));
            if (kt < 4) nf[kt + 4] = nG[(kt + 4) * 64];   // depth-4 prefetch
            b8 n0 = nW[kt * 64];                           // nt=0 from LDS
            aR0  = MFMA(whr[0][kt], hfrag, aR0);
            aR1  = MFMA(whr[1][kt], hfrag, aR1);
            aZ0  = MFMA(whz[0][kt], hfrag, aZ0);
            aZ1  = MFMA(whz[1][kt], hfrag, aZ1);
            aNH0 = MFMA(n0, hfrag, aNH0);
            aNH1 = MFMA(nf[kt], hfrag, aNH1);              // nt=1 from L2 (last: waits late)
        }

        // gate fusion: weights pre-scaled (-log2e for r,z; 2*log2e for n) -> raw v_exp_f32
        __bf16* hn = hbB + (cur ^ 1) * 4096;
        b4 v0, v1;
        #pragma unroll
        for (int j = 0; j < 4; ++j) {
            float r = __builtin_amdgcn_rcpf(1.0f + __builtin_amdgcn_exp2f(aR0[j]));
            float z = __builtin_amdgcn_rcpf(1.0f + __builtin_amdgcn_exp2f(aZ0[j]));
            float u = fmaf(r, aNH0[j], aNX0[j]);
            float n = fmaf(-2.0f, __builtin_amdgcn_rcpf(1.0f + __builtin_amdgcn_exp2f(u)), 1.0f);
            float hv = n + z * (h0[j] - n);
            h0[j] = hv; v0[j] = (__bf16)hv;

            r = __builtin_amdgcn_rcpf(1.0f + __builtin_amdgcn_exp2f(aR1[j]));
            z = __builtin_amdgcn_rcpf(1.0f + __builtin_amdgcn_exp2f(aZ1[j]));
            u = fmaf(r, aNH1[j], aNX1[j]);
            n = fmaf(-2.0f, __builtin_amdgcn_rcpf(1.0f + __builtin_amdgcn_exp2f(u)), 1.0f);
            hv = n + z * (h1[j] - n);
            h1[j] = hv; v1[j] = (__bf16)hv;
        }
        *(b4*)(hn + l15 * 256 + ((32 * w + 0  + 4 * lq) ^ wswz)) = v0;
        *(b4*)(hn + l15 * 256 + ((32 * w + 16 + 4 * lq) ^ wswz)) = v1;

        xf = xn;
        cur ^= 1;
        __syncthreads();
    }

    // ---- write forward h (f32 regs) into lastb cols [0,256) ----
    {
        b4 v0, v1;
        #pragma unroll
        for (int j = 0; j < 4; ++j) { v0[j] = (__bf16)h0[j]; v1[j] = (__bf16)h1[j]; }
        *(b4*)(&lastb[l15][0] + ((32 * w + 0  + 4 * lq) ^ wswz)) = v0;
        *(b4*)(&lastb[l15][0] + ((32 * w + 16 + 4 * lq) ^ wswz)) = v1;
    }

    // ---- backward cell (h0=0, one step on x[:,127,:]) -> lastb cols [256,512) ----
    {
        const int trow = tid >> 5;           // 0..15
        const int cb = tid & 31;
        const float4* xr = (const float4*)(x + (blockRow + trow) * WDIM * FDIM + 127 * FDIM);
        float4 xv0 = xr[0], xv1 = xr[1];
        const float4* wb = (const float4*)Wih_b;
        #pragma unroll
        for (int jj = 0; jj < 8; ++jj) {
            int ch = cb + 32 * jj;
            float4 a0 = wb[ch * 2],               a1 = wb[ch * 2 + 1];
            float4 b0 = wb[(HDIM + ch) * 2],      b1 = wb[(HDIM + ch) * 2 + 1];
            float4 c0v = wb[(2 * HDIM + ch) * 2], c1 = wb[(2 * HDIM + ch) * 2 + 1];
            float ir = bih_b[ch]
                + xv0.x * a0.x + xv0.y * a0.y + xv0.z * a0.z + xv0.w * a0.w
                + xv1.x * a1.x + xv1.y * a1.y + xv1.z * a1.z + xv1.w * a1.w;
            float iz = bih_b[HDIM + ch]
                + xv0.x * b0.x + xv0.y * b0.y + xv0.z * b0.z + xv0.w * b0.w
                + xv1.x * b1.x + xv1.y * b1.y + xv1.z * b1.z + xv1.w * b1.w;
            float inn = bih_b[2 * HDIM + ch]
                + xv0.x * c0v.x + xv0.y * c0v.y + xv0.z * c0v.z + xv0.w * c0v.w
                + xv1.x * c1.x + xv1.y * c1.y + xv1.z * c1.z + xv1.w * c1.w;
            float r = sig_(ir + bhh_b[ch]);
            float z = sig_(iz + bhh_b[HDIM + ch]);
            float n = tanh_(fmaf(r, bhh_b[2 * HDIM + ch], inn));
            float hbw = (1.0f - z) * n;
            int c2 = HDIM + ch;
            lastb[trow][c2 ^ ((trow & 7) << 3)] = (__bf16)hbw;
        }
    }
    __syncthreads();

    // ---- projection: y = gelu(last @ Wp^T + bp); wave w -> cols [32w,32w+32) ----
    {
        f32x4 pacc[2];
        #pragma unroll
        for (int nt = 0; nt < 2; ++nt) {
            int col = 32 * w + nt * 16 + l15;
            float b = bp[col];
            pacc[nt][0] = b; pacc[nt][1] = b; pacc[nt][2] = b; pacc[nt][3] = b;
        }
        #pragma unroll
        for (int kt = 0; kt < 16; ++kt) {
            int c = (kt * 32 + lq * 8) ^ ((l15 & 7) << 3);
            b8 a = *(const b8*)&lastb[l15][c];
            #pragma unroll
            for (int nt = 0; nt < 2; ++nt)
                pacc[nt] = MFMA(a, wsWP[((2 * w + nt) * 16 + kt) * 64 + lane], pacc[nt]);
        }
        #pragma unroll
        for (int nt = 0; nt < 2; ++nt) {
            int col = 32 * w + nt * 16 + l15;
            #pragma unroll
            for (int j = 0; j < 4; ++j) {
                int row = lq * 4 + j;
                float v = pacc[nt][j];
                ybuf[row][col] = 0.5f * v * (1.0f + erff(v * 0.70710678118f));
            }
        }
    }
    __syncthreads();

    // ---- LayerNorm: one wave per 2 rows ----
    #pragma unroll
    for (int rr = 0; rr < 2; ++rr) {
        int row = 2 * w + rr;
        float v[4];
        float s = 0.0f, sq = 0.0f;
        #pragma unroll
        for (int m = 0; m < 4; ++m) {
            v[m] = ybuf[row][lane + 64 * m];
            s += v[m];
            sq += v[m] * v[m];
        }
        #pragma unroll
        for (int off = 32; off >= 1; off >>= 1) {
            s  += __shfl_xor(s, off, 64);
            sq += __shfl_xor(sq, off, 64);
        }
        float mu = s * (1.0f / 256.0f);
        float var = sq * (1.0f / 256.0f) - mu * mu;
        float rs = rsqrtf(var + 1e-5f);
        float* orow = out + (blockRow + row) * HDIM;
        #pragma unroll
        for (int m = 0; m < 4; ++m) {
            int cc = lane + 64 * m;
            orow[cc] = (v[m] - mu) * rs * gamma[cc] + beta[cc];
        }
    }
}

extern "C" void kernel_launch(void* const* d_in, const int* in_sizes, int n_in,
                              void* d_out, int out_size, void* d_ws, size_t ws_size,
                              hipStream_t stream)
{
    const float* x     = (const float*)d_in[0];
    const float* Wih_f = (const float*)d_in[1];
    const float* Whh_f = (const float*)d_in[2];
    const float* bih_f = (const float*)d_in[3];
    const float* bhh_f = (const float*)d_in[4];
    const float* Wih_b = (const float*)d_in[5];
    // d_in[6] = Whh_b unused: h0=0 so gh_b = bhh_b exactly
    const float* bih_b = (const float*)d_in[7];
    const float* bhh_b = (const float*)d_in[8];
    const float* Wp    = (const float*)d_in[9];
    const float* bp    = (const float*)d_in[10];
    const float* gamma = (const float*)d_in[11];
    const float* beta  = (const float*)d_in[12];
    float* out = (float*)d_out;
    unsigned char* ws = (unsigned char*)d_ws;

    // allow 80KB dynamic LDS (host-side attribute, graph-capture safe)
    hipFuncSetAttribute((const void*)gru_main_kernel,
                        hipFuncAttributeMaxDynamicSharedMemorySize, SMEM_BYTES);

    const int packItems = 16384 + 8192 + 3072 + 16384 + 262144;   // 306176
    hipLaunchKernelGGL(pack_kernel, dim3((packItems + 255) / 256), dim3(256), 0, stream,
                       x, Wih_f, Whh_f, bih_f, bhh_f, Wp, ws);
    hipLaunchKernelGGL(gru_main_kernel, dim3(BDIM / 16), dim3(512), SMEM_BYTES, stream,
                       x, bhh_f, Wih_b, bih_b, bhh_b, bp, gamma, beta, ws, out);
}

// Round 13
// 216.951 us; speedup vs baseline: 1.3522x; 1.3522x over previous
//
#include <hip/hip_runtime.h>
#include <hip/hip_bf16.h>

#define BDIM 2048
#define WDIM 128
#define FDIM 8
#define HDIM 256

typedef __bf16 b8 __attribute__((ext_vector_type(8)));
typedef __bf16 b4 __attribute__((ext_vector_type(4)));
typedef float f32x4 __attribute__((ext_vector_type(4)));
typedef long l64;                       // 8 fp8 = one fp8 MFMA frag per lane

#define L2E  1.44269504088896f
#define L2E2 2.88539008177793f

// workspace layout (bytes), 16B aligned
#define OFF_RZ8 0                       // 256 fp8 frags * 512B (r,z Whh, x -log2e)
#define OFF_NB  131072                  // 128 bf16 frags * 1KB (n Whh, x 2*log2e) - pinned AGPR
#define OFF_WI8 262144                  // 32 fp8 frags * 512B  (Wih r,z + bias in k=8)
#define OFF_WIN 278528                  // 16 bf16 frags * 1KB  (Wih n + bias in k=8)
#define OFF_WP  294912                  // 256 bf16 frags * 1KB (Wp, unscaled)
#define OFF_XB  557056                  // 2048*128*8 bf16 = 4194304
// total 4,751,360 B

#define MFMA(a,b,c)  __builtin_amdgcn_mfma_f32_16x16x32_bf16((a),(b),(c),0,0,0)
#define MFMA8(a,b,c) __builtin_amdgcn_mfma_f32_16x16x32_fp8_fp8((a),(b),(c),0,0,0)

static __device__ __forceinline__ float sig_(float v) {      // tail only
    return __builtin_amdgcn_rcpf(1.0f + __expf(-v));
}
static __device__ __forceinline__ float tanh_(float v) {     // tail only
    return fmaf(-2.0f, __builtin_amdgcn_rcpf(1.0f + __expf(2.0f * v)), 1.0f);
}

// pack 8 f32 -> 8 fp8 e4m3 (OCP on gfx950), bytes ascending
static __device__ __forceinline__ l64 pk8(const float* v) {
    int lo = __builtin_amdgcn_cvt_pk_fp8_f32(v[0], v[1], 0, false);
    lo = __builtin_amdgcn_cvt_pk_fp8_f32(v[2], v[3], lo, true);
    int hi = __builtin_amdgcn_cvt_pk_fp8_f32(v[4], v[5], 0, false);
    hi = __builtin_amdgcn_cvt_pk_fp8_f32(v[6], v[7], hi, true);
    return ((l64)(unsigned)hi << 32) | (unsigned)lo;
}
static __device__ __forceinline__ l64 b8_to_f8(b8 v) {
    float f[8];
    #pragma unroll
    for (int e = 0; e < 8; ++e) f[e] = (float)v[e];
    return pk8(f);
}

// ---------------- pack: weights/x -> MFMA fragments ----------------
// A-frag (16x16x32): lane l holds A[i = l&15][k = kt*32 + (l>>4)*8 + e]
// B-frag:            lane l holds B[k = kt*32 + (l>>4)*8 + e][j = l&15]
__global__ void pack_kernel(const float* __restrict__ x,
                            const float* __restrict__ Wih_f,
                            const float* __restrict__ Whh_f,
                            const float* __restrict__ bih_f,
                            const float* __restrict__ bhh_f,
                            const float* __restrict__ Wp,
                            unsigned char* __restrict__ ws)
{
    int idx = blockIdx.x * 256 + threadIdx.x;
    if (idx < 16384) {                       // r,z Whh fp8: f = (w*4+2g+nt)*8+kt, x(-log2e)
        int l = idx & 63, f = idx >> 6;
        int kt = f & 7, nt = (f >> 3) & 1, g = (f >> 4) & 1, w = f >> 5;
        int gch = g * HDIM + 32 * w + 16 * nt + (l & 15);
        int kb = kt * 32 + (l >> 4) * 8;
        float v[8];
        #pragma unroll
        for (int e = 0; e < 8; ++e) v[e] = -L2E * Whh_f[gch * HDIM + kb + e];
        ((l64*)(ws + OFF_RZ8))[idx] = pk8(v);
    } else if (idx < 24576) {                // n Whh bf16: f = (w*2+nt)*8+kt, x(2*log2e)
        int j = idx - 16384;
        int l = j & 63, f = j >> 6;
        int kt = f & 7, nt = (f >> 3) & 1, w = f >> 4;
        int gch = 2 * HDIM + 32 * w + 16 * nt + (l & 15);
        int kb = kt * 32 + (l >> 4) * 8;
        b8 v;
        #pragma unroll
        for (int e = 0; e < 8; ++e) v[e] = (__bf16)(L2E2 * Whh_f[gch * HDIM + kb + e]);
        ((b8*)(ws + OFF_NB))[j] = v;
    } else if (idx < 26624) {                // Wih r,z fp8: f = w*4+2g+nt (bias at k=8)
        int j = idx - 24576;
        int l = j & 63, f = j >> 6;
        int nt = f & 1, g = (f >> 1) & 1, w = f >> 2;
        int gch = g * HDIM + 32 * w + 16 * nt + (l & 15);
        int lq = l >> 4;
        float v[8];
        #pragma unroll
        for (int e = 0; e < 8; ++e) v[e] = 0.0f;
        if (lq == 0) {
            #pragma unroll
            for (int e = 0; e < 8; ++e) v[e] = -L2E * Wih_f[gch * FDIM + e];
        } else if (lq == 1) {
            v[0] = -L2E * (bih_f[gch] + bhh_f[gch]);   // pairs with 1.0 in x frag k=8
        }
        ((l64*)(ws + OFF_WI8))[j] = pk8(v);
    } else if (idx < 27648) {                // Wih n bf16: f = w*2+nt (bias at k=8)
        int j = idx - 26624;
        int l = j & 63, f = j >> 6;
        int nt = f & 1, w = f >> 1;
        int gch = 2 * HDIM + 32 * w + 16 * nt + (l & 15);
        int lq = l >> 4;
        b8 v;
        #pragma unroll
        for (int e = 0; e < 8; ++e) v[e] = (__bf16)0.0f;
        if (lq == 0) {
            #pragma unroll
            for (int e = 0; e < 8; ++e) v[e] = (__bf16)(L2E2 * Wih_f[gch * FDIM + e]);
        } else if (lq == 1) {
            v[0] = (__bf16)(L2E2 * bih_f[gch]);
        }
        ((b8*)(ws + OFF_WIN))[j] = v;
    } else if (idx < 44032) {                // Wp B-frags (bf16, unscaled)
        int j = idx - 27648;
        int l = j & 63, nk = j >> 6;
        int NT = nk >> 4, kt = nk & 15;
        int col = NT * 16 + (l & 15);
        int kb = kt * 32 + (l >> 4) * 8;
        b8 v;
        #pragma unroll
        for (int e = 0; e < 8; ++e) v[e] = (__bf16)Wp[col * (2 * HDIM) + kb + e];
        ((b8*)(ws + OFF_WP))[j] = v;
    } else if (idx < 44032 + 262144) {       // x -> bf16 rows [row][t][8]
        int j = idx - 44032;
        const float* src = x + j * 8;
        b8 v;
        #pragma unroll
        for (int e = 0; e < 8; ++e) v[e] = (__bf16)src[e];
        ((b8*)(ws + OFF_XB))[j] = v;
    }
}

// ---------------- fused GRU, hybrid fp8(r,z)/bf16(n): 128 blocks x 512 thr (8 waves) ----------------
// Wave w owns gate channels [32w, 32w+32). ALL weights pinned (144 regs):
// r,z Whh fp8 (64) VGPR, n Whh bf16 (64) AGPR, Wih fp8 (8) + bf16 (8).
// h master f32 in regs; h exchanged as bf16 plane (n path) + fp8 plane (r,z path).
// Per-step LDS: 96KB read + 12KB write (was 200KB in R10).
__global__ __launch_bounds__(512, 2)
void gru_main_kernel(const float* __restrict__ x,
                     const float* __restrict__ bhh_f,
                     const float* __restrict__ Wih_b, const float* __restrict__ bih_b,
                     const float* __restrict__ bhh_b,
                     const float* __restrict__ bp,
                     const float* __restrict__ gamma, const float* __restrict__ beta,
                     const unsigned char* __restrict__ ws,
                     float* __restrict__ out)
{
    // smem: loop: [0,16K) h bf16 dbuf (2x8KB) ; [16K,24K) h fp8 dbuf (2x4KB)
    //       tail: [0,16K) lastb[16][512] bf16 ; [16K,32K) ybuf[16][256] f32
    __shared__ __align__(16) unsigned char smem[32768];
    __bf16* hbB = (__bf16*)smem;
    unsigned char* hb8 = smem + 16384;
    __bf16 (*lastb)[2 * HDIM] = (__bf16(*)[2 * HDIM])smem;
    float  (*ybuf)[HDIM]      = (float(*)[HDIM])(smem + 16384);

    const int tid = threadIdx.x, lane = tid & 63, w = tid >> 6;
    const int l15 = lane & 15, lq = lane >> 4;
    const int blockRow = blockIdx.x * 16;

    const l64* wsRZ8 = (const l64*)(ws + OFF_RZ8);
    const b8*  wsNB  = (const b8*)(ws + OFF_NB);
    const l64* wsWI8 = (const l64*)(ws + OFF_WI8);
    const b8*  wsWIN = (const b8*)(ws + OFF_WIN);
    const b8*  wsWP  = (const b8*)(ws + OFF_WP);
    const b8*  xB    = (const b8*)(ws + OFF_XB);

    const f32x4 zero4 = {0.f, 0.f, 0.f, 0.f};

    // zero both h dbuf planes (24KB): 512 threads x 16B x 3
    *(f32x4*)(smem + tid * 16) = zero4;
    *(f32x4*)(smem + 8192 + tid * 16) = zero4;
    *(f32x4*)(smem + 16384 + tid * 16) = zero4;

    // pinned weights: r,z fp8 (32 frags), n bf16 (16 frags, AGPR), Wih fp8(4)+bf16(2)
    l64 whr8[2][8], whz8[2][8], wir8[2], wiz8[2];
    b8 wnnB[2][8], winB[2];
    #pragma unroll
    for (int nt = 0; nt < 2; ++nt) {
        #pragma unroll
        for (int kt = 0; kt < 8; ++kt) {
            whr8[nt][kt] = wsRZ8[((w * 4 + 0 + nt) * 8 + kt) * 64 + lane];
            whz8[nt][kt] = wsRZ8[((w * 4 + 2 + nt) * 8 + kt) * 64 + lane];
            wnnB[nt][kt] = wsNB[((w * 2 + nt) * 8 + kt) * 64 + lane];
        }
        wir8[nt] = wsWI8[(w * 4 + 0 + nt) * 64 + lane];
        wiz8[nt] = wsWI8[(w * 4 + 2 + nt) * 64 + lane];
        winB[nt] = wsWIN[(w * 2 + nt) * 64 + lane];
    }
    #pragma unroll
    for (int nt = 0; nt < 2; ++nt) {
        #pragma unroll
        for (int kt = 0; kt < 8; ++kt) {
            asm volatile("" : "+v"(whr8[nt][kt]));
            asm volatile("" : "+v"(whz8[nt][kt]));
            asm volatile("" : "+a"(wnnB[nt][kt]));
        }
        asm volatile("" : "+v"(wir8[nt]));
        asm volatile("" : "+v"(wiz8[nt]));
        asm volatile("" : "+v"(winB[nt]));
    }

    // bhh_n accumulator-init, x 2*log2e (C reg j <-> gatech 32w+16nt+4lq+j)
    float4 t0v = *(const float4*)&bhh_f[2 * HDIM + 32 * w + 0  + 4 * lq];
    float4 t1v = *(const float4*)&bhh_f[2 * HDIM + 32 * w + 16 + 4 * lq];
    f32x4 bnv0, bnv1;
    bnv0[0] = L2E2 * t0v.x; bnv0[1] = L2E2 * t0v.y; bnv0[2] = L2E2 * t0v.z; bnv0[3] = L2E2 * t0v.w;
    bnv1[0] = L2E2 * t1v.x; bnv1[1] = L2E2 * t1v.y; bnv1[2] = L2E2 * t1v.z; bnv1[3] = L2E2 * t1v.w;

    // constant part of x B-frag: k=8 -> 1.0 (bias multiplier), rest 0
    b8 xc;
    #pragma unroll
    for (int e = 0; e < 8; ++e) xc[e] = (__bf16)0.0f;
    if (lq == 1) xc[0] = (__bf16)1.0f;

    // h master state f32 in regs: (row=l15, ch=32w+16nt+4lq+j)
    f32x4 h0 = zero4, h1 = zero4;

    const int kswz = (8 * lq) ^ ((l15 & 7) << 3);     // read swizzle (elems/bytes)
    const int wswz = (l15 & 7) << 3;                  // write swizzle
    const b8* xRow = xB + (blockRow + l15) * WDIM;

    // prefetch x for t=0
    b8 xf = xc;
    if (lane < 16) xf = xRow[0];

    __syncthreads();

    int cur = 0;
    for (int t = 0; t < WDIM; ++t) {
        b8 xn = xc;
        if (lane < 16) xn = xRow[(t + 1) & 127];

        // fp8 copy of x frag (k=8 slot 1.0 converts exactly)
        l64 xf8 = b8_to_f8(xf);

        // x-part MFMAs first (reg-only; fill post-barrier ds_read window)
        f32x4 aR0 = MFMA8(wir8[0], xf8, zero4);
        f32x4 aR1 = MFMA8(wir8[1], xf8, zero4);
        f32x4 aZ0 = MFMA8(wiz8[0], xf8, zero4);
        f32x4 aZ1 = MFMA8(wiz8[1], xf8, zero4);
        f32x4 aNX0 = MFMA(winB[0], xf, zero4);
        f32x4 aNX1 = MFMA(winB[1], xf, zero4);
        f32x4 aNH0 = bnv0, aNH1 = bnv1;

        const __bf16* hcB = hbB + cur * 4096 + l15 * 256;          // bf16 plane (elems)
        const unsigned char* hc8 = hb8 + cur * 4096 + l15 * 256;   // fp8 plane (bytes)
        #pragma unroll
        for (int kt = 0; kt < 8; ++kt) {
            b8 hfB  = *(const b8*)(hcB + ((kt << 5) ^ kswz));
            l64 hf8 = *(const l64*)(hc8 + ((kt << 5) ^ kswz));
            aR0  = MFMA8(whr8[0][kt], hf8, aR0);
            aR1  = MFMA8(whr8[1][kt], hf8, aR1);
            aZ0  = MFMA8(whz8[0][kt], hf8, aZ0);
            aZ1  = MFMA8(whz8[1][kt], hf8, aZ1);
            aNH0 = MFMA(wnnB[0][kt], hfB, aNH0);
            aNH1 = MFMA(wnnB[1][kt], hfB, aNH1);
        }

        // gate fusion (pre-scaled -> raw exp2); h master f32; write both planes
        __bf16* hnB = hbB + (cur ^ 1) * 4096;
        unsigned char* hn8 = hb8 + (cur ^ 1) * 4096 + l15 * 256;
        b4 v0, v1;
        float hv0[4], hv1[4];
        #pragma unroll
        for (int j = 0; j < 4; ++j) {
            float r = __builtin_amdgcn_rcpf(1.0f + __builtin_amdgcn_exp2f(aR0[j]));
            float z = __builtin_amdgcn_rcpf(1.0f + __builtin_amdgcn_exp2f(aZ0[j]));
            float u = fmaf(r, aNH0[j], aNX0[j]);
            float n = fmaf(-2.0f, __builtin_amdgcn_rcpf(1.0f + __builtin_amdgcn_exp2f(u)), 1.0f);
            float hv = n + z * (h0[j] - n);
            h0[j] = hv; v0[j] = (__bf16)hv; hv0[j] = hv;

            r = __builtin_amdgcn_rcpf(1.0f + __builtin_amdgcn_exp2f(aR1[j]));
            z = __builtin_amdgcn_rcpf(1.0f + __builtin_amdgcn_exp2f(aZ1[j]));
            u = fmaf(r, aNH1[j], aNX1[j]);
            n = fmaf(-2.0f, __builtin_amdgcn_rcpf(1.0f + __builtin_amdgcn_exp2f(u)), 1.0f);
            hv = n + z * (h1[j] - n);
            h1[j] = hv; v1[j] = (__bf16)hv; hv1[j] = hv;
        }
        *(b4*)(hnB + l15 * 256 + ((32 * w + 0  + 4 * lq) ^ wswz)) = v0;
        *(b4*)(hnB + l15 * 256 + ((32 * w + 16 + 4 * lq) ^ wswz)) = v1;
        int p0 = __builtin_amdgcn_cvt_pk_fp8_f32(hv0[0], hv0[1], 0, false);
        p0 = __builtin_amdgcn_cvt_pk_fp8_f32(hv0[2], hv0[3], p0, true);
        int p1 = __builtin_amdgcn_cvt_pk_fp8_f32(hv1[0], hv1[1], 0, false);
        p1 = __builtin_amdgcn_cvt_pk_fp8_f32(hv1[2], hv1[3], p1, true);
        *(int*)(hn8 + ((32 * w + 0  + 4 * lq) ^ wswz)) = p0;
        *(int*)(hn8 + ((32 * w + 16 + 4 * lq) ^ wswz)) = p1;

        xf = xn;
        cur ^= 1;
        __syncthreads();
    }

    // ---- write forward h (f32 regs) into lastb cols [0,256) ----
    {
        b4 v0, v1;
        #pragma unroll
        for (int j = 0; j < 4; ++j) { v0[j] = (__bf16)h0[j]; v1[j] = (__bf16)h1[j]; }
        *(b4*)(&lastb[l15][0] + ((32 * w + 0  + 4 * lq) ^ wswz)) = v0;
        *(b4*)(&lastb[l15][0] + ((32 * w + 16 + 4 * lq) ^ wswz)) = v1;
    }

    // ---- backward cell (h0=0, one step on x[:,127,:]) -> lastb cols [256,512) ----
    {
        const int trow = tid >> 5;           // 0..15
        const int cb = tid & 31;
        const float4* xr = (const float4*)(x + (blockRow + trow) * WDIM * FDIM + 127 * FDIM);
        float4 xv0 = xr[0], xv1 = xr[1];
        const float4* wb = (const float4*)Wih_b;
        #pragma unroll
        for (int jj = 0; jj < 8; ++jj) {
            int ch = cb + 32 * jj;
            float4 a0 = wb[ch * 2],               a1 = wb[ch * 2 + 1];
            float4 b0 = wb[(HDIM + ch) * 2],      b1 = wb[(HDIM + ch) * 2 + 1];
            float4 c0v = wb[(2 * HDIM + ch) * 2], c1 = wb[(2 * HDIM + ch) * 2 + 1];
            float ir = bih_b[ch]
                + xv0.x * a0.x + xv0.y * a0.y + xv0.z * a0.z + xv0.w * a0.w
                + xv1.x * a1.x + xv1.y * a1.y + xv1.z * a1.z + xv1.w * a1.w;
            float iz = bih_b[HDIM + ch]
                + xv0.x * b0.x + xv0.y * b0.y + xv0.z * b0.z + xv0.w * b0.w
                + xv1.x * b1.x + xv1.y * b1.y + xv1.z * b1.z + xv1.w * b1.w;
            float inn = bih_b[2 * HDIM + ch]
                + xv0.x * c0v.x + xv0.y * c0v.y + xv0.z * c0v.z + xv0.w * c0v.w
                + xv1.x * c1.x + xv1.y * c1.y + xv1.z * c1.z + xv1.w * c1.w;
            float r = sig_(ir + bhh_b[ch]);
            float z = sig_(iz + bhh_b[HDIM + ch]);
            float n = tanh_(fmaf(r, bhh_b[2 * HDIM + ch], inn));
            float hbw = (1.0f - z) * n;
            int c2 = HDIM + ch;
            lastb[trow][c2 ^ ((trow & 7) << 3)] = (__bf16)hbw;
        }
    }
    __syncthreads();

    // ---- projection: y = gelu(last @ Wp^T + bp); wave w -> cols [32w,32w+32) ----
    {
        f32x4 pacc[2];
        #pragma unroll
        for (int nt = 0; nt < 2; ++nt) {
            int col = 32 * w + nt * 16 + l15;
            float b = bp[col];
            pacc[nt][0] = b; pacc[nt][1] = b; pacc[nt][2] = b; pacc[nt][3] = b;
        }
        #pragma unroll
        for (int kt = 0; kt < 16; ++kt) {
            int c = (kt * 32 + lq * 8) ^ ((l15 & 7) << 3);
            b8 a = *(const b8*)&lastb[l15][c];
            #pragma unroll
            for (int nt = 0; nt < 2; ++nt)
                pacc[nt] = MFMA(a, wsWP[((2 * w + nt) * 16 + kt) * 64 + lane], pacc[nt]);
        }
        #pragma unroll
        for (int nt = 0; nt < 2; ++nt) {
            int col = 32 * w + nt * 16 + l15;
            #pragma unroll
            for (int j = 0; j < 4; ++j) {
                int row = lq * 4 + j;
                float v = pacc[nt][j];
                ybuf[row][col] = 0.5f * v * (1.0f + erff(v * 0.70710678118f));
            }
        }
    }
    __syncthreads();

    // ---- LayerNorm: one wave per 2 rows ----
    #pragma unroll
    for (int rr = 0; rr < 2; ++rr) {
        int row = 2 * w + rr;
        float v[4];
        float s = 0.0f, sq = 0.0f;
        #pragma unroll
        for (int m = 0; m < 4; ++m) {
            v[m] = ybuf[row][lane + 64 * m];
            s += v[m];
            sq += v[m] * v[m];
        }
        #pragma unroll
        for (int off = 32; off >= 1; off >>= 1) {
            s  += __shfl_xor(s, off, 64);
            sq += __shfl_xor(sq, off, 64);
        }
        float mu = s * (1.0f / 256.0f);
        float var = sq * (1.0f / 256.0f) - mu * mu;
        float rs = rsqrtf(var + 1e-5f);
        float* orow = out + (blockRow + row) * HDIM;
        #pragma unroll
        for (int m = 0; m < 4; ++m) {
            int cc = lane + 64 * m;
            orow[cc] = (v[m] - mu) * rs * gamma[cc] + beta[cc];
        }
    }
}

extern "C" void kernel_launch(void* const* d_in, const int* in_sizes, int n_in,
                              void* d_out, int out_size, void* d_ws, size_t ws_size,
                              hipStream_t stream)
{
    const float* x     = (const float*)d_in[0];
    const float* Wih_f = (const float*)d_in[1];
    const float* Whh_f = (const float*)d_in[2];
    const float* bih_f = (const float*)d_in[3];
    const float* bhh_f = (const float*)d_in[4];
    const float* Wih_b = (const float*)d_in[5];
    // d_in[6] = Whh_b unused: h0=0 so gh_b = bhh_b exactly
    const float* bih_b = (const float*)d_in[7];
    const float* bhh_b = (const float*)d_in[8];
    const float* Wp    = (const float*)d_in[9];
    const float* bp    = (const float*)d_in[10];
    const float* gamma = (const float*)d_in[11];
    const float* beta  = (const float*)d_in[12];
    float* out = (float*)d_out;
    unsigned char* ws = (unsigned char*)d_ws;

    const int packItems = 16384 + 8192 + 2048 + 1024 + 16384 + 262144;   // 306176
    hipLaunchKernelGGL(pack_kernel, dim3((packItems + 255) / 256), dim3(256), 0, stream,
                       x, Wih_f, Whh_f, bih_f, bhh_f, Wp, ws);
    hipLaunchKernelGGL(gru_main_kernel, dim3(BDIM / 16), dim3(512), 0, stream,
                       x, bhh_f, Wih_b, bih_b, bhh_b, bp, gamma, beta, ws, out);
}